// Round 4
// baseline (195.834 us; speedup 1.0000x reference)
//
#include <hip/hip_runtime.h>
#include <hip/hip_bf16.h>
#include <math.h>

#define NB   2048
#define CIN  192
#define HW   361
#define NTH  512          // 8 waves; each wave owns 48 px (3 n-tiles of 16)

typedef float  f32x4  __attribute__((ext_vector_type(4)));
typedef short  s16x8  __attribute__((ext_vector_type(8)));
typedef float  f32x4u __attribute__((ext_vector_type(4), aligned(4)));

__device__ __forceinline__ unsigned short f2bf_bits(float f) {
    __hip_bfloat16 h = __float2bfloat16(f);   // RNE
    unsigned short s;
    __builtin_memcpy(&s, &h, sizeof(s));
    return s;
}
__device__ __forceinline__ unsigned int packbf(float lo, float hi) {
    return (unsigned int)f2bf_bits(lo) | ((unsigned int)f2bf_bits(hi) << 16);
}

// tanh-form GELU via hardware exp
__device__ __forceinline__ float gelu_fast(float x) {
    float inner = x * fmaf(0.044715f, x * x, 1.0f);
    float t = 1.5957691216057308f * inner;
    if (t > 40.f) return x;
    float e = __expf(t);
    return x * (e / (e + 1.0f));
}

__global__ __launch_bounds__(NTH, 4)
void policy_head_mfma(const float* __restrict__ inputs,
                      const float* __restrict__ mask,
                      const float* __restrict__ mask_sum,
                      const float* __restrict__ w1p, const float* __restrict__ b1p,
                      const float* __restrict__ w1g, const float* __restrict__ b1g,
                      const float* __restrict__ beta_g,
                      const float* __restrict__ w_lin, const float* __restrict__ b_lin,
                      const float* __restrict__ beta2,
                      const float* __restrict__ w2p, const float* __restrict__ b2p,
                      float* __restrict__ out) {
    // wlds32: [64 rows][100 dwords] bf16-pairs of conv1 weights (rows 0-31 w1p, 32-63 w1g)
    __shared__ unsigned int wlds32[64 * 100];     // 25.6 KB
    // xt32: transposed X tile, [384 px][16 dwords] bf16 channel-pairs, quad-swizzled
    __shared__ unsigned int xt32[384 * 16];       // 24.6 KB
    __shared__ float small[160];                  // b1p | b1g | beta_g | beta2 | w2p
    __shared__ float redA[256];
    __shared__ float redB[256];
    __shared__ float pooled[96];
    __shared__ float linout[32];

    const int tid  = threadIdx.x;
    const int b    = blockIdx.x;
    const int w    = tid >> 6;
    const int lane = tid & 63;
    const int g4   = lane >> 4;     // 0..3
    const int c16  = lane & 15;     // 0..15

    const float* xb = inputs + (size_t)b * (CIN * HW);

    // ---- staging-task geometry: task = (channel-pair p, px-group g of 4) ----
    const int p   = ((w & 3) << 2) + (lane >> 4);   // cpair 0..15 (4 per wave)
    const int gl  = lane & 15;
    const int W2  = w >> 2;                          // 0/1
    int gs[3];
    #pragma unroll
    for (int k = 0; k < 3; ++k) gs[k] = W2 * 16 + 32 * k + gl;   // covers g 0..95

    float va[3][4], vb[3][4];

    auto loadx = [&](int kk) {
        const float* tb = xb + (size_t)(kk * 32 + 2 * p) * HW;
        #pragma unroll
        for (int k = 0; k < 3; ++k) {
            int g = gs[k];
            if (g <= 89) {
                f32x4u r0 = *(const f32x4u*)(tb + 4 * g);
                f32x4u r1 = *(const f32x4u*)(tb + HW + 4 * g);
                #pragma unroll
                for (int j = 0; j < 4; ++j) { va[k][j] = r0[j]; vb[k][j] = r1[j]; }
            } else if (g == 90) {
                va[k][0] = tb[360];
                vb[k][0] = tb[HW + 360];
            }
        }
    };

    auto write_xt = [&]() {
        #pragma unroll
        for (int k = 0; k < 3; ++k) {
            int g  = gs[k];
            int qb = (((p >> 2) ^ (g & 3)) << 2) | (p & 3);   // swizzled dword-in-row
            if (g <= 89) {
                #pragma unroll
                for (int j = 0; j < 4; ++j)
                    xt32[(4 * g + j) * 16 + qb] = packbf(va[k][j], vb[k][j]);
            } else if (g == 90) {
                xt32[360 * 16 + qb] = packbf(va[k][0], vb[k][0]);
            }
        }
    };

    // ---- fire first tile's loads, then stage weights (latency overlap) ----
    loadx(0);

    #pragma unroll
    for (int k = 0; k < 6; ++k) {                 // 64 rows x 48 float4 = 3072 tasks
        int i = tid + k * NTH;
        int o = i / 48, cq = i - o * 48;
        const float* src = (o < 32) ? (w1p + o * CIN + 4 * cq)
                                    : (w1g + (o - 32) * CIN + 4 * cq);
        float4 v = *(const float4*)src;
        wlds32[o * 100 + 2 * cq]     = packbf(v.x, v.y);
        wlds32[o * 100 + 2 * cq + 1] = packbf(v.z, v.w);
    }
    if (tid < 32)       small[tid] = b1p[tid];
    else if (tid < 64)  small[tid] = b1g[tid - 32];
    else if (tid < 96)  small[tid] = beta_g[tid - 64];
    else if (tid < 128) small[tid] = beta2[tid - 96];
    else if (tid < 160) small[tid] = w2p[tid - 128];

    // ---- per-lane pixel mapping for MFMA fragments ----
    int   px[3], bidx[3];
    float mv[3];
    bool  valid[3];
    #pragma unroll
    for (int nt = 0; nt < 3; ++nt) {
        px[nt]    = w * 48 + nt * 16 + c16;
        valid[nt] = (px[nt] < HW);
        mv[nt]    = valid[nt] ? mask[(size_t)b * HW + px[nt]] : 0.f;
        bidx[nt]  = px[nt] * 16 + ((g4 ^ (c16 >> 2)) << 2);   // matches write swizzle
    }

    f32x4 acc[4][3];
    #pragma unroll
    for (int mt = 0; mt < 4; ++mt)
        #pragma unroll
        for (int nt = 0; nt < 3; ++nt)
            acc[mt][nt] = (f32x4){0.f, 0.f, 0.f, 0.f};

    __syncthreads();   // weights staged; xt about to be written

    for (int kk = 0; kk < 6; ++kk) {
        write_xt();                      // waits on this tile's global loads
        __syncthreads();                 // xt ready
        if (kk < 5) loadx(kk + 1);       // fire next tile's loads (overlap w/ MFMA)

        s16x8 bfr[3];
        #pragma unroll
        for (int nt = 0; nt < 3; ++nt)
            bfr[nt] = *(const s16x8*)&xt32[bidx[nt]];

        #pragma unroll
        for (int mt = 0; mt < 4; ++mt) {
            s16x8 a = *(const s16x8*)&wlds32[(mt * 16 + c16) * 100 + kk * 16 + 4 * g4];
            #pragma unroll
            for (int nt = 0; nt < 3; ++nt)
                acc[mt][nt] = __builtin_amdgcn_mfma_f32_16x16x32_bf16(a, bfr[nt], acc[mt][nt], 0, 0, 0);
        }
        if (kk < 5) __syncthreads();     // readers done before next overwrite
    }

    const float ms  = mask_sum[b];
    const float off = (sqrtf(ms) - 28.0f) * 0.1f;

    // ---- g-head: mask, GELU, pool (sum + max over px) ----
    #pragma unroll
    for (int mt = 2; mt < 4; ++mt) {
        #pragma unroll
        for (int r = 0; r < 4; ++r) {
            int og = (mt - 2) * 16 + g4 * 4 + r;              // 0..31
            float bb = small[32 + og] + small[64 + og];       // b1g + beta_g
            float s = 0.f, mx = -1e30f;
            #pragma unroll
            for (int nt = 0; nt < 3; ++nt) {
                float v = gelu_fast((acc[mt][nt][r] + bb) * mv[nt]);
                if (!valid[nt]) v = 0.f;
                s += v;
                float cand = valid[nt] ? (v + mv[nt] - 1.f) : -1e30f;
                mx = fmaxf(mx, cand);
            }
            #pragma unroll
            for (int o = 1; o < 16; o <<= 1) {
                s += __shfl_xor(s, o, 64);
                mx = fmaxf(mx, __shfl_xor(mx, o, 64));
            }
            if (c16 == 0) { redA[og * 8 + w] = s; redB[og * 8 + w] = mx; }
        }
    }
    __syncthreads();

    if (tid < 32) {
        float s = 0.f, mx = -1e30f;
        #pragma unroll
        for (int j = 0; j < 8; ++j) {
            s += redA[tid * 8 + j];
            mx = fmaxf(mx, redB[tid * 8 + j]);
        }
        float mean = s / ms;
        pooled[tid]      = mean;
        pooled[32 + tid] = mean * off;
        pooled[64 + tid] = mx;
    }
    __syncthreads();

    if (tid < 32) {
        float a = b_lin[tid];
        #pragma unroll
        for (int j = 0; j < 96; ++j) a = fmaf(pooled[j], w_lin[tid * 96 + j], a);
        linout[tid] = a;
    }
    __syncthreads();

    // ---- p-head: bias+lin+beta2, mask, GELU, dot with w2p ----
    float pv[3] = {0.f, 0.f, 0.f};
    #pragma unroll
    for (int mt = 0; mt < 2; ++mt) {
        #pragma unroll
        for (int r = 0; r < 4; ++r) {
            int op = mt * 16 + g4 * 4 + r;                    // 0..31
            float bb = small[op] + linout[op] + small[96 + op];
            float wo = small[128 + op];
            #pragma unroll
            for (int nt = 0; nt < 3; ++nt)
                pv[nt] += gelu_fast((acc[mt][nt][r] + bb) * mv[nt]) * wo;
        }
    }
    const float b2 = b2p[0];
    float logit[3];
    #pragma unroll
    for (int nt = 0; nt < 3; ++nt) {
        float t = pv[nt];
        t += __shfl_xor(t, 16, 64);
        t += __shfl_xor(t, 32, 64);
        logit[nt] = t + b2 - (1.f - mv[nt]) * 5000.f;
    }

    // ---- log-softmax over 361 px ----
    float lmax = -1e30f;
    #pragma unroll
    for (int nt = 0; nt < 3; ++nt)
        if (valid[nt]) lmax = fmaxf(lmax, logit[nt]);
    #pragma unroll
    for (int o = 1; o < 64; o <<= 1) lmax = fmaxf(lmax, __shfl_xor(lmax, o, 64));
    if (lane == 0) redA[w] = lmax;
    __syncthreads();
    float gmax = -1e30f;
    #pragma unroll
    for (int j = 0; j < 8; ++j) gmax = fmaxf(gmax, redA[j]);

    float es = 0.f;
    #pragma unroll
    for (int nt = 0; nt < 3; ++nt)
        if (valid[nt] && g4 == 0) es += __expf(logit[nt] - gmax);
    #pragma unroll
    for (int o = 1; o < 64; o <<= 1) es += __shfl_xor(es, o, 64);
    if (lane == 0) redB[w] = es;
    __syncthreads();
    float tot = 0.f;
    #pragma unroll
    for (int j = 0; j < 8; ++j) tot += redB[j];
    const float lt = __logf(tot) + gmax;

    if (g4 == 0) {
        #pragma unroll
        for (int nt = 0; nt < 3; ++nt)
            if (valid[nt]) out[(size_t)b * HW + px[nt]] = logit[nt] - lt;
    }
}

extern "C" void kernel_launch(void* const* d_in, const int* in_sizes, int n_in,
                              void* d_out, int out_size, void* d_ws, size_t ws_size,
                              hipStream_t stream) {
    const float* inputs   = (const float*)d_in[0];
    const float* mask     = (const float*)d_in[1];
    const float* mask_sum = (const float*)d_in[2];
    const float* w1p      = (const float*)d_in[3];
    const float* b1p      = (const float*)d_in[4];
    const float* w1g      = (const float*)d_in[5];
    const float* b1g      = (const float*)d_in[6];
    const float* beta_g   = (const float*)d_in[7];
    const float* w_lin    = (const float*)d_in[8];
    const float* b_lin    = (const float*)d_in[9];
    const float* beta2    = (const float*)d_in[10];
    const float* w2p      = (const float*)d_in[11];
    const float* b2p      = (const float*)d_in[12];
    float* out = (float*)d_out;

    policy_head_mfma<<<dim3(NB), dim3(NTH), 0, stream>>>(
        inputs, mask, mask_sum, w1p, b1p, w1g, b1g, beta_g,
        w_lin, b_lin, beta2, w2p, b2p, out);
}

// Round 5
// 173.654 us; speedup vs baseline: 1.1277x; 1.1277x over previous
//
#include <hip/hip_runtime.h>
#include <hip/hip_bf16.h>
#include <math.h>

#define NBLK   256          // one block per CU; 8 batch elements each
#define EPB    8
#define CIN    192
#define HW     361
#define NTH    512          // 8 waves
#define NSTAGE 48           // EPB * 6 K-tiles
#define TILE_BYTES 46208    // 32 ch * 361 px * 4 B
#define SLOTS  2888         // TILE_BYTES / 16
#define PSLOTS 3072         // padded to 48 instr * 64 lanes

typedef float f32x4 __attribute__((ext_vector_type(4)));
typedef short s16x8 __attribute__((ext_vector_type(8)));

__device__ __forceinline__ unsigned short f2bf_bits(float f) {
    __hip_bfloat16 h = __float2bfloat16(f);   // RNE
    unsigned short s;
    __builtin_memcpy(&s, &h, sizeof(s));
    return s;
}
__device__ __forceinline__ unsigned int packbf(float lo, float hi) {
    return (unsigned int)f2bf_bits(lo) | ((unsigned int)f2bf_bits(hi) << 16);
}

// tanh-form GELU via hardware exp
__device__ __forceinline__ float gelu_fast(float x) {
    float inner = x * fmaf(0.044715f, x * x, 1.0f);
    float t = 1.5957691216057308f * inner;
    if (t > 40.f) return x;
    float e = __expf(t);
    return x * (e / (e + 1.0f));
}

// async global -> LDS, 16B per lane; LDS dest is wave-uniform base + lane*16
#define GLD_LDS16(g, l) __builtin_amdgcn_global_load_lds( \
    (const __attribute__((address_space(1))) unsigned int*)(g), \
    (__attribute__((address_space(3))) unsigned int*)(l), 16, 0, 0)

__global__ __launch_bounds__(NTH, 2)
void policy_head_pipe(const float* __restrict__ inputs,
                      const float* __restrict__ mask,
                      const float* __restrict__ mask_sum,
                      const float* __restrict__ w1p, const float* __restrict__ b1p,
                      const float* __restrict__ w1g, const float* __restrict__ b1g,
                      const float* __restrict__ beta_g,
                      const float* __restrict__ w_lin, const float* __restrict__ b_lin,
                      const float* __restrict__ beta2,
                      const float* __restrict__ w2p, const float* __restrict__ b2p,
                      float* __restrict__ out) {
    __shared__ __align__(16) float xbuf[2][PSLOTS * 4];  // 96 KB: f32 X tiles [32ch][361px]
    __shared__ unsigned int wlds[64 * 100];              // 25.6 KB bf16-pair conv1 weights
    __shared__ float wlin_t[96 * 32];                    // 12 KB, transposed [j][o]
    __shared__ float mlds[EPB * HW];                     // 11.6 KB masks for all 8 elements
    __shared__ float small[224];  // 0:b1p 32:b1g 64:beta_g 96:beta2 128:w2p 160:b_lin 192:ms[8] 200:b2p
    __shared__ float redA[256], redB[256], pooled[96], linout[32];

    const int tid  = threadIdx.x;
    const int bid  = blockIdx.x;
    const int wv   = tid >> 6;
    const int lane = tid & 63;
    const int g4   = lane >> 4;
    const int c16  = lane & 15;

    // per-lane pixel map (element-independent)
    int px[3], pxc[3];
    bool valid[3];
    #pragma unroll
    for (int nt = 0; nt < 3; ++nt) {
        px[nt]    = wv * 48 + nt * 16 + c16;
        valid[nt] = (px[nt] < HW);
        pxc[nt]   = valid[nt] ? px[nt] : (HW - 1);
    }

    // ---------------- prologue staging (ordinary loads; drained before pipeline) ----------------
    #pragma unroll
    for (int k = 0; k < 6; ++k) {                        // conv1 weights -> bf16 pairs
        int i = tid + k * NTH;                           // 0..3071 (64 rows x 48 float4)
        int o = i / 48, cq = i - o * 48;
        const float* src = (o < 32) ? (w1p + o * CIN + 4 * cq)
                                    : (w1g + (o - 32) * CIN + 4 * cq);
        float4 v = *(const float4*)src;
        wlds[o * 100 + 2 * cq]     = packbf(v.x, v.y);
        wlds[o * 100 + 2 * cq + 1] = packbf(v.z, v.w);
    }
    #pragma unroll
    for (int k = 0; k < 6; ++k) {                        // w_lin transposed
        int i = tid + k * NTH;                           // 0..3071
        int j = i >> 5, o = i & 31;
        wlin_t[i] = w_lin[o * 96 + j];
    }
    #pragma unroll
    for (int k = 0; k < 6; ++k) {                        // masks for all 8 elements
        int i = tid + k * NTH;
        if (i < EPB * HW) mlds[i] = mask[(size_t)bid * EPB * HW + i];
    }
    if (tid < 32)        small[tid] = b1p[tid];
    else if (tid < 64)   small[tid] = b1g[tid - 32];
    else if (tid < 96)   small[tid] = beta_g[tid - 64];
    else if (tid < 128)  small[tid] = beta2[tid - 96];
    else if (tid < 160)  small[tid] = w2p[tid - 128];
    else if (tid < 192)  small[tid] = b_lin[tid - 160];
    else if (tid < 200)  small[tid] = mask_sum[bid * EPB + (tid - 192)];
    else if (tid == 200) small[tid] = b2p[0];

    __syncthreads();   // full drain: vmcnt==0 on every wave from here on

    // ---------------- async tile staging ----------------
    const char* in_base = (const char*)inputs;
    auto stage_gll = [&](int t, int pb) {
        const char* src = in_base + ((size_t)(bid * EPB + t / 6) * CIN * HW
                                     + (size_t)(t % 6) * 32 * HW) * 4;
        #pragma unroll
        for (int j = 0; j < 6; ++j) {
            int slotbase = (j * 8 + wv) * 64;
            int cs = slotbase + lane;
            if (cs > SLOTS - 1) cs = SLOTS - 1;          // clamp source; dest pad never read
            GLD_LDS16(src + (size_t)cs * 16, &xbuf[pb][slotbase * 4]);
        }
    };

    f32x4 acc[4][3];

    stage_gll(0, 0);
    stage_gll(1, 1);
    asm volatile("s_waitcnt vmcnt(6)" ::: "memory");     // tile 0 landed; tile 1 in flight
    __builtin_amdgcn_s_barrier();

    auto lbar = [] {
        asm volatile("s_waitcnt lgkmcnt(0)" ::: "memory");
        __builtin_amdgcn_s_barrier();
    };

    // ---------------- main pipeline: 48 K-tile stages ----------------
    for (int t = 0; t < NSTAGE; ++t) {
        const int pb = t & 1;
        const int kk = t % 6;

        if (kk == 0) {
            #pragma unroll
            for (int mt = 0; mt < 4; ++mt)
                #pragma unroll
                for (int nt = 0; nt < 3; ++nt)
                    acc[mt][nt] = (f32x4){0.f, 0.f, 0.f, 0.f};
        }

        // ---- compute stage t from xbuf[pb] ----
        {
            const float* xf = xbuf[pb];
            s16x8 bfr[3];
            #pragma unroll
            for (int nt = 0; nt < 3; ++nt) {
                float v[8];
                #pragma unroll
                for (int i = 0; i < 8; ++i)
                    v[i] = xf[(8 * g4 + i) * HW + pxc[nt]];
                #pragma unroll
                for (int i = 0; i < 8; ++i)
                    bfr[nt][i] = (short)f2bf_bits(v[i]);
            }
            #pragma unroll
            for (int mt = 0; mt < 4; ++mt) {
                s16x8 a = *(const s16x8*)&wlds[(mt * 16 + c16) * 100 + kk * 16 + 4 * g4];
                #pragma unroll
                for (int nt = 0; nt < 3; ++nt)
                    acc[mt][nt] = __builtin_amdgcn_mfma_f32_16x16x32_bf16(a, bfr[nt], acc[mt][nt], 0, 0, 0);
            }
        }

        asm volatile("" ::: "memory");
        __builtin_amdgcn_s_barrier();                    // all waves done reading xbuf[pb]

        if (t + 2 < NSTAGE) {
            stage_gll(t + 2, pb);                        // refill the buffer just freed
            asm volatile("s_waitcnt vmcnt(6)" ::: "memory");   // tile t+1 landed; t+2 in flight
        } else {
            asm volatile("s_waitcnt vmcnt(0)" ::: "memory");
        }
        __builtin_amdgcn_s_barrier();                    // next buffer ready for everyone

        // ---- per-element epilogue (lgkm-only barriers: vmem prefetch stays in flight) ----
        if (kk == 5) {
            const int e = t / 6;
            const float ms  = small[192 + e];
            const float off = (sqrtf(ms) - 28.0f) * 0.1f;
            float mv[3];
            #pragma unroll
            for (int nt = 0; nt < 3; ++nt)
                mv[nt] = valid[nt] ? mlds[e * HW + pxc[nt]] : 0.f;

            // g-head: mask, GELU, pool
            #pragma unroll
            for (int mt = 2; mt < 4; ++mt) {
                #pragma unroll
                for (int r = 0; r < 4; ++r) {
                    int og = (mt - 2) * 16 + g4 * 4 + r;
                    float bb = small[32 + og] + small[64 + og];
                    float s = 0.f, mx = -1e30f;
                    #pragma unroll
                    for (int nt = 0; nt < 3; ++nt) {
                        float v = gelu_fast((acc[mt][nt][r] + bb) * mv[nt]);
                        if (!valid[nt]) v = 0.f;
                        s += v;
                        float cand = valid[nt] ? (v + mv[nt] - 1.f) : -1e30f;
                        mx = fmaxf(mx, cand);
                    }
                    #pragma unroll
                    for (int o = 1; o < 16; o <<= 1) {
                        s += __shfl_xor(s, o, 64);
                        mx = fmaxf(mx, __shfl_xor(mx, o, 64));
                    }
                    if (c16 == 0) { redA[og * 8 + wv] = s; redB[og * 8 + wv] = mx; }
                }
            }
            lbar();

            if (tid < 32) {
                float s = 0.f, mx = -1e30f;
                #pragma unroll
                for (int j = 0; j < 8; ++j) {
                    s += redA[tid * 8 + j];
                    mx = fmaxf(mx, redB[tid * 8 + j]);
                }
                float mean = s / ms;
                pooled[tid]      = mean;
                pooled[32 + tid] = mean * off;
                pooled[64 + tid] = mx;
            }
            lbar();

            if (tid < 32) {
                float a = small[160 + tid];              // b_lin
                #pragma unroll
                for (int j = 0; j < 96; ++j) a = fmaf(pooled[j], wlin_t[j * 32 + tid], a);
                linout[tid] = a;
            }
            lbar();

            // p-head
            float pv[3] = {0.f, 0.f, 0.f};
            #pragma unroll
            for (int mt = 0; mt < 2; ++mt) {
                #pragma unroll
                for (int r = 0; r < 4; ++r) {
                    int op = mt * 16 + g4 * 4 + r;
                    float bb = small[op] + linout[op] + small[96 + op];
                    float wo = small[128 + op];
                    #pragma unroll
                    for (int nt = 0; nt < 3; ++nt)
                        pv[nt] += gelu_fast((acc[mt][nt][r] + bb) * mv[nt]) * wo;
                }
            }
            const float b2 = small[200];
            float logit[3];
            #pragma unroll
            for (int nt = 0; nt < 3; ++nt) {
                float s = pv[nt];
                s += __shfl_xor(s, 16, 64);
                s += __shfl_xor(s, 32, 64);
                logit[nt] = s + b2 - (1.f - mv[nt]) * 5000.f;
            }

            // log-softmax over 361 px
            float lmax = -1e30f;
            #pragma unroll
            for (int nt = 0; nt < 3; ++nt)
                if (valid[nt]) lmax = fmaxf(lmax, logit[nt]);
            #pragma unroll
            for (int o = 1; o < 64; o <<= 1) lmax = fmaxf(lmax, __shfl_xor(lmax, o, 64));
            if (lane == 0) redA[wv] = lmax;
            lbar();
            float gmax = -1e30f;
            #pragma unroll
            for (int j = 0; j < 8; ++j) gmax = fmaxf(gmax, redA[j]);

            float es = 0.f;
            #pragma unroll
            for (int nt = 0; nt < 3; ++nt)
                if (valid[nt] && g4 == 0) es += __expf(logit[nt] - gmax);
            #pragma unroll
            for (int o = 1; o < 64; o <<= 1) es += __shfl_xor(es, o, 64);
            if (lane == 0) redB[wv] = es;
            lbar();
            float tot = 0.f;
            #pragma unroll
            for (int j = 0; j < 8; ++j) tot += redB[j];
            const float lt = __logf(tot) + gmax;

            if (g4 == 0) {
                #pragma unroll
                for (int nt = 0; nt < 3; ++nt)
                    if (valid[nt])
                        out[((size_t)bid * EPB + e) * HW + px[nt]] = logit[nt] - lt;
            }
            lbar();   // redA/redB/pooled/linout free for next element
        }
    }
}

extern "C" void kernel_launch(void* const* d_in, const int* in_sizes, int n_in,
                              void* d_out, int out_size, void* d_ws, size_t ws_size,
                              hipStream_t stream) {
    const float* inputs   = (const float*)d_in[0];
    const float* mask     = (const float*)d_in[1];
    const float* mask_sum = (const float*)d_in[2];
    const float* w1p      = (const float*)d_in[3];
    const float* b1p      = (const float*)d_in[4];
    const float* w1g      = (const float*)d_in[5];
    const float* b1g      = (const float*)d_in[6];
    const float* beta_g   = (const float*)d_in[7];
    const float* w_lin    = (const float*)d_in[8];
    const float* b_lin    = (const float*)d_in[9];
    const float* beta2    = (const float*)d_in[10];
    const float* w2p      = (const float*)d_in[11];
    const float* b2p      = (const float*)d_in[12];
    float* out = (float*)d_out;

    policy_head_pipe<<<dim3(NBLK), dim3(NTH), 0, stream>>>(
        inputs, mask, mask_sum, w1p, b1p, w1g, b1g, beta_g,
        w_lin, b_lin, beta2, w2p, b2p, out);
}

// Round 6
// 173.574 us; speedup vs baseline: 1.1282x; 1.0005x over previous
//
#include <hip/hip_runtime.h>
#include <hip/hip_bf16.h>
#include <math.h>

#define NB    2048
#define EPB   4
#define NBLK  (NB / EPB)     // 512 blocks -> 2 per CU
#define CIN   192
#define HW    361
#define NTH   256            // 4 waves; each wave owns 96 px

typedef float f32x4  __attribute__((ext_vector_type(4)));
typedef short s16x8  __attribute__((ext_vector_type(8)));
typedef float f32x4u __attribute__((ext_vector_type(4), aligned(4)));

__device__ __forceinline__ unsigned short f2bf_bits(float f) {
    __hip_bfloat16 h = __float2bfloat16(f);   // RNE
    unsigned short s;
    __builtin_memcpy(&s, &h, sizeof(s));
    return s;
}
__device__ __forceinline__ unsigned int packbf(float lo, float hi) {
    return (unsigned int)f2bf_bits(lo) | ((unsigned int)f2bf_bits(hi) << 16);
}

__device__ __forceinline__ float gelu_fast(float x) {
    float inner = x * fmaf(0.044715f, x * x, 1.0f);
    float t = 1.5957691216057308f * inner;
    if (t > 40.f) return x;
    float e = __expf(t);
    return x * (e / (e + 1.0f));
}

__global__ __launch_bounds__(NTH, 2)
void policy_head_wp(const float* __restrict__ inputs,
                    const float* __restrict__ mask,
                    const float* __restrict__ mask_sum,
                    const float* __restrict__ w1p, const float* __restrict__ b1p,
                    const float* __restrict__ w1g, const float* __restrict__ b1g,
                    const float* __restrict__ beta_g,
                    const float* __restrict__ w_lin, const float* __restrict__ b_lin,
                    const float* __restrict__ beta2,
                    const float* __restrict__ w2p, const float* __restrict__ b2p,
                    float* __restrict__ out) {
    // wave-private double-buffered bf16 X tiles: [wave][buf][96 px][16 dwords]
    __shared__ unsigned int xt[4][2][96 * 16];    // 48 KiB
    __shared__ unsigned int wlds[64 * 100];       // 25.6 KiB bf16-pair conv1 weights
    __shared__ float redA[32 * 4], redB[32 * 4];  // 1 KiB
    __shared__ float small[224];   // b1p|b1g|beta_g|beta2|w2p|b_lin|ms[4]|b2p
    __shared__ float pooled[96], linout[32];

    const int tid  = threadIdx.x;
    const int bid  = blockIdx.x;
    const int wv   = tid >> 6;
    const int lane = tid & 63;
    const int g4   = lane >> 4;
    const int c16  = lane & 15;

    // per-lane pixel map: 6 n-tiles of 16 within the wave's 96-px slice
    int px[6];  bool valid[6];
    #pragma unroll
    for (int nt = 0; nt < 6; ++nt) {
        px[nt]    = wv * 96 + nt * 16 + c16;
        valid[nt] = (px[nt] < HW);
    }

    const float* xb0 = inputs + (size_t)bid * EPB * CIN * HW;

    f32x4 rA[12];
    auto loadT = [&](int e, int kk) {
        const float* tb = xb0 + ((size_t)e * CIN + kk * 32 + 2 * c16) * HW;
        #pragma unroll
        for (int j = 0; j < 6; ++j) {
            int p0 = wv * 96 + 16 * j + 4 * g4;
            if (p0 > HW - 4) p0 = HW - 4;            // end-of-array guard (junk region)
            rA[2 * j]     = *(const f32x4u*)(tb + p0);
            rA[2 * j + 1] = *(const f32x4u*)(tb + HW + p0);
        }
    };

    // ---- fire element-0 tile-0 loads first, then stage weights (overlap) ----
    loadT(0, 0);

    #pragma unroll
    for (int k = 0; k < 12; ++k) {                 // 64 rows x 48 float4 = 3072 tasks
        int i = tid + k * NTH;
        int o = i / 48, cq = i - o * 48;
        const float* src = (o < 32) ? (w1p + o * CIN + 4 * cq)
                                    : (w1g + (o - 32) * CIN + 4 * cq);
        float4 v = *(const float4*)src;
        wlds[o * 100 + 2 * cq]     = packbf(v.x, v.y);
        wlds[o * 100 + 2 * cq + 1] = packbf(v.z, v.w);
    }
    if (tid < 32)        small[tid] = b1p[tid];
    else if (tid < 64)   small[tid] = b1g[tid - 32];
    else if (tid < 96)   small[tid] = beta_g[tid - 64];
    else if (tid < 128)  small[tid] = beta2[tid - 96];
    else if (tid < 160)  small[tid] = w2p[tid - 128];
    else if (tid < 192)  small[tid] = b_lin[tid - 160];
    else if (tid < 196)  small[tid] = mask_sum[bid * EPB + (tid - 192)];
    else if (tid == 196) small[tid] = b2p[0];

    auto lbar = [] {
        asm volatile("s_waitcnt lgkmcnt(0)" ::: "memory");
        __builtin_amdgcn_s_barrier();
    };
    lbar();   // lgkm-only: tile-0 global loads stay in flight

    const int qb = 4 * (g4 ^ ((c16 & 3) ^ (c16 >> 2)));   // read-side swizzle (per-lane const)

    for (int e = 0; e < EPB; ++e) {
        // mask prefetch for this element (consumed in epilogue)
        float mv[6];
        #pragma unroll
        for (int nt = 0; nt < 6; ++nt)
            mv[nt] = valid[nt] ? mask[((size_t)bid * EPB + e) * HW + px[nt]] : 0.f;

        f32x4 acc[4][6];
        #pragma unroll
        for (int mt = 0; mt < 4; ++mt)
            #pragma unroll
            for (int nt = 0; nt < 6; ++nt)
                acc[mt][nt] = (f32x4){0.f, 0.f, 0.f, 0.f};

        #pragma unroll
        for (int kk = 0; kk < 6; ++kk) {
            unsigned int* xw = &xt[wv][kk & 1][0];

            // cvt + swizzled write of tile kk (waits this tile's global loads)
            #pragma unroll
            for (int j = 0; j < 6; ++j) {
                #pragma unroll
                for (int d = 0; d < 4; ++d) {
                    int lp = 16 * j + 4 * g4 + d;
                    int qc = c16 ^ (((d ^ g4) & 3) << 2);
                    xw[lp * 16 + qc] = packbf(rA[2 * j][d], rA[2 * j + 1][d]);
                }
            }

            // issue next tile's loads (stay in flight under MFMA + next cvt)
            if (kk < 5)            loadT(e, kk + 1);
            else if (e + 1 < EPB)  loadT(e + 1, 0);

            // B fragments (conflict-free b128) + A fragments + 24 MFMA
            s16x8 bfr[6];
            #pragma unroll
            for (int nt = 0; nt < 6; ++nt)
                bfr[nt] = *(const s16x8*)&xw[(nt * 16 + c16) * 16 + qb];
            #pragma unroll
            for (int mt = 0; mt < 4; ++mt) {
                s16x8 a = *(const s16x8*)&wlds[(mt * 16 + c16) * 100 + kk * 16 + 4 * g4];
                #pragma unroll
                for (int nt = 0; nt < 6; ++nt)
                    acc[mt][nt] = __builtin_amdgcn_mfma_f32_16x16x32_bf16(a, bfr[nt], acc[mt][nt], 0, 0, 0);
            }
        }

        // ---------------- epilogue (lgkm-only barriers) ----------------
        const float ms  = small[192 + e];
        const float off = (sqrtf(ms) - 28.0f) * 0.1f;

        // g-head: mask, GELU, pool (sum + max)
        #pragma unroll
        for (int mt = 2; mt < 4; ++mt) {
            #pragma unroll
            for (int r = 0; r < 4; ++r) {
                int og = (mt - 2) * 16 + g4 * 4 + r;
                float bb = small[32 + og] + small[64 + og];
                float s = 0.f, mx = -1e30f;
                #pragma unroll
                for (int nt = 0; nt < 6; ++nt) {
                    float v = gelu_fast((acc[mt][nt][r] + bb) * mv[nt]);
                    if (!valid[nt]) v = 0.f;
                    s += v;
                    float cand = valid[nt] ? (v + mv[nt] - 1.f) : -1e30f;
                    mx = fmaxf(mx, cand);
                }
                #pragma unroll
                for (int o = 1; o < 16; o <<= 1) {
                    s += __shfl_xor(s, o, 64);
                    mx = fmaxf(mx, __shfl_xor(mx, o, 64));
                }
                if (c16 == 0) { redA[og * 4 + wv] = s; redB[og * 4 + wv] = mx; }
            }
        }
        lbar();

        if (tid < 32) {
            float s = 0.f, mx = -1e30f;
            #pragma unroll
            for (int j = 0; j < 4; ++j) {
                s += redA[tid * 4 + j];
                mx = fmaxf(mx, redB[tid * 4 + j]);
            }
            float mean = s / ms;
            pooled[tid]      = mean;
            pooled[32 + tid] = mean * off;
            pooled[64 + tid] = mx;
        }
        lbar();

        if (tid < 32) {
            float a = small[160 + tid];
            #pragma unroll
            for (int j = 0; j < 96; ++j) a = fmaf(pooled[j], w_lin[tid * 96 + j], a);
            linout[tid] = a;
        }
        lbar();

        // p-head
        float pv[6] = {0.f, 0.f, 0.f, 0.f, 0.f, 0.f};
        #pragma unroll
        for (int mt = 0; mt < 2; ++mt) {
            #pragma unroll
            for (int r = 0; r < 4; ++r) {
                int op = mt * 16 + g4 * 4 + r;
                float bb = small[op] + linout[op] + small[96 + op];
                float wo = small[128 + op];
                #pragma unroll
                for (int nt = 0; nt < 6; ++nt)
                    pv[nt] += gelu_fast((acc[mt][nt][r] + bb) * mv[nt]) * wo;
            }
        }
        const float b2 = small[196];
        float logit[6];
        #pragma unroll
        for (int nt = 0; nt < 6; ++nt) {
            float s = pv[nt];
            s += __shfl_xor(s, 16, 64);
            s += __shfl_xor(s, 32, 64);
            logit[nt] = s + b2 - (1.f - mv[nt]) * 5000.f;
        }

        // log-softmax over 361 px
        float lmax = -1e30f;
        #pragma unroll
        for (int nt = 0; nt < 6; ++nt)
            if (valid[nt]) lmax = fmaxf(lmax, logit[nt]);
        #pragma unroll
        for (int o = 1; o < 64; o <<= 1) lmax = fmaxf(lmax, __shfl_xor(lmax, o, 64));
        if (lane == 0) redA[wv] = lmax;
        lbar();
        float gmax = -1e30f;
        #pragma unroll
        for (int j = 0; j < 4; ++j) gmax = fmaxf(gmax, redA[j]);

        float es = 0.f;
        #pragma unroll
        for (int nt = 0; nt < 6; ++nt)
            if (valid[nt] && g4 == 0) es += __expf(logit[nt] - gmax);
        #pragma unroll
        for (int o = 1; o < 64; o <<= 1) es += __shfl_xor(es, o, 64);
        if (lane == 0) redB[wv] = es;
        lbar();
        float tot = 0.f;
        #pragma unroll
        for (int j = 0; j < 4; ++j) tot += redB[j];
        const float lt = __logf(tot) + gmax;

        if (g4 == 0) {
            #pragma unroll
            for (int nt = 0; nt < 6; ++nt)
                if (valid[nt])
                    out[((size_t)bid * EPB + e) * HW + px[nt]] = logit[nt] - lt;
        }
        lbar();   // redA/redB safe for next element
    }
}

extern "C" void kernel_launch(void* const* d_in, const int* in_sizes, int n_in,
                              void* d_out, int out_size, void* d_ws, size_t ws_size,
                              hipStream_t stream) {
    const float* inputs   = (const float*)d_in[0];
    const float* mask     = (const float*)d_in[1];
    const float* mask_sum = (const float*)d_in[2];
    const float* w1p      = (const float*)d_in[3];
    const float* b1p      = (const float*)d_in[4];
    const float* w1g      = (const float*)d_in[5];
    const float* b1g      = (const float*)d_in[6];
    const float* beta_g   = (const float*)d_in[7];
    const float* w_lin    = (const float*)d_in[8];
    const float* b_lin    = (const float*)d_in[9];
    const float* beta2    = (const float*)d_in[10];
    const float* w2p      = (const float*)d_in[11];
    const float* b2p      = (const float*)d_in[12];
    float* out = (float*)d_out;

    policy_head_wp<<<dim3(NBLK), dim3(NTH), 0, stream>>>(
        inputs, mask, mask_sum, w1p, b1p, w1g, b1g, beta_g,
        w_lin, b_lin, beta2, w2p, b2p, out);
}